// Round 1
// baseline (6912.982 us; speedup 1.0000x reference)
//
#include <hip/hip_runtime.h>
#include <cstdint>
#include <cstddef>

// ---------------------------------------------------------------------------
// Graphormer-ish encoder forward, MI355X (gfx950).
// Round 0: correctness-first baseline with bf16 MFMA GEMMs (m93-style 128x128
// tile), on-the-fly attention bias (sp-MLP collapsed to per-head affine),
// LDS-staged attention with wave softmax.
// ---------------------------------------------------------------------------

typedef __attribute__((ext_vector_type(8))) short bf16x8;
typedef __attribute__((ext_vector_type(4))) float f32x4;

static constexpr int D    = 768;
static constexpr int H    = 12;
static constexpr int S    = 512;
static constexpr int NN   = 511;
static constexpr int B    = 8;
static constexpr int FFN  = 3072;
static constexpr int ROWS = B * S;   // 4096

__device__ __forceinline__ short f2b(float x) {
    union { float f; uint32_t u; } c; c.f = x;
    uint32_t r = (c.u + 0x7fffu + ((c.u >> 16) & 1u)) >> 16;  // RNE
    return (short)(uint16_t)r;
}
__device__ __forceinline__ float b2f(short h) {
    union { uint32_t u; float f; } c; c.u = ((uint32_t)(uint16_t)h) << 16;
    return c.f;
}
__device__ __forceinline__ float b2f_lo(uint32_t u) {
    union { uint32_t u; float f; } c; c.u = u << 16; return c.f;
}
__device__ __forceinline__ float b2f_hi(uint32_t u) {
    union { uint32_t u; float f; } c; c.u = u & 0xffff0000u; return c.f;
}
__device__ __forceinline__ float gelu_f(float x) {
    return 0.5f * x * (1.0f + erff(x * 0.7071067811865476f));
}

// ---------------------------------------------------------------------------
// h[b,0,:] = graph_token; h[b,1+n,:] = node_emb[x[b,n,0]]
// ---------------------------------------------------------------------------
__global__ __launch_bounds__(256) void embed_kernel(
    const int* __restrict__ x, const float* __restrict__ emb,
    const float* __restrict__ gtok, float* __restrict__ h)
{
    int row = blockIdx.x;                 // b*S + s
    int b = row >> 9, s = row & (S - 1);
    const float* src = (s == 0) ? gtok : (emb + (size_t)x[b * NN + (s - 1)] * D);
    float* dst = h + (size_t)row * D;
    int t = threadIdx.x;
    dst[t]       = src[t];
    dst[t + 256] = src[t + 256];
    dst[t + 512] = src[t + 512];
}

// ---------------------------------------------------------------------------
// sp-MLP collapses to affine per head: A[h] = sum_k w1[k]*w2[k][h],
// C[h] = sum_k b1[k]*w2[k][h] + b2[h]
// ---------------------------------------------------------------------------
__global__ void ac_kernel(const float* __restrict__ w1, const float* __restrict__ b1,
                          const float* __restrict__ w2, const float* __restrict__ b2,
                          float* __restrict__ ac)
{
    int h = threadIdx.x;
    if (h < H) {
        float a = 0.f, c = 0.f;
        for (int k = 0; k < 128; ++k) { a += w1[k] * w2[k * H + h]; c += b1[k] * w2[k * H + h]; }
        ac[h] = a; ac[16 + h] = c + b2[h];
    }
}

// ---------------------------------------------------------------------------
// LayerNorm over D=768, one row per block (256 threads, 3 elems each)
// ---------------------------------------------------------------------------
__global__ __launch_bounds__(256) void ln_kernel(
    const float* __restrict__ in, const float* __restrict__ sc,
    const float* __restrict__ bi, float* __restrict__ out)
{
    int row = blockIdx.x, t = threadIdx.x;
    const float* x = in + (size_t)row * D;
    float e0 = x[t], e1 = x[t + 256], e2 = x[t + 512];
    float s  = e0 + e1 + e2;
    float sq = e0 * e0 + e1 * e1 + e2 * e2;
    #pragma unroll
    for (int off = 1; off < 64; off <<= 1) { s += __shfl_xor(s, off); sq += __shfl_xor(sq, off); }
    __shared__ float red[8];
    int w = t >> 6, lane = t & 63;
    if (lane == 0) { red[w] = s; red[4 + w] = sq; }
    __syncthreads();
    s  = red[0] + red[1] + red[2] + red[3];
    sq = red[4] + red[5] + red[6] + red[7];
    float m   = s * (1.f / D);
    float inv = rsqrtf(sq * (1.f / D) - m * m + 1e-5f);
    float* o = out + (size_t)row * D;
    o[t]       = (e0 - m) * inv * sc[t]       + bi[t];
    o[t + 256] = (e1 - m) * inv * sc[t + 256] + bi[t + 256];
    o[t + 512] = (e2 - m) * inv * sc[t + 512] + bi[t + 512];
}

// ---------------------------------------------------------------------------
// bf16 MFMA GEMM: out = epilogue(A[M,K] @ W[K,nper] + bias)
// 128x128 block tile, 4 waves (2x2), each wave 64x64 = 4x4 frags of 16x16x32.
// Up to 3 weight matrices (QKV fused along grid.y); outBase strided by
// which*ROWS*nper. Epilogue: (+bias)*alpha [which0 only], gelu, +resid.
// Verified layouts (learn_hip): A frag row=l&15,k=(l>>4)*8+j; B frag
// col=l&15, same k; C/D col=lane&15, row=(lane>>4)*4+reg.
// ---------------------------------------------------------------------------
__global__ __launch_bounds__(256) void gemm_kernel(
    const float* __restrict__ A,
    const float* __restrict__ W0, const float* __restrict__ W1, const float* __restrict__ W2,
    const float* __restrict__ Bb0, const float* __restrict__ Bb1, const float* __restrict__ Bb2,
    float* __restrict__ outBase, const float* __restrict__ resid,
    int K, int nper, float alpha0, int dogelu)
{
    __shared__ short As[128][40];   // [row][k], +8 pad (80B stride, 16B aligned)
    __shared__ short Bs[128][40];   // [col][k] (transposed stage)
    int tid  = threadIdx.x;
    int lane = tid & 63;
    int w    = tid >> 6;
    int row0 = blockIdx.x * 128;
    int n0   = blockIdx.y * 128;
    int which = n0 / nper;
    int ncol0 = n0 - which * nper;
    const float* W  = (which == 0) ? W0  : ((which == 1) ? W1  : W2);
    const float* Bv = (which == 0) ? Bb0 : ((which == 1) ? Bb1 : Bb2);
    float* out  = outBase + (size_t)which * ROWS * nper;
    float alpha = (which == 0) ? alpha0 : 1.0f;

    int wr = (w >> 1) * 64;      // wave row offset in tile
    int wc = (w & 1) * 64;       // wave col offset in tile
    int fr = lane & 15;
    int kb = (lane >> 4) * 8;

    f32x4 acc[4][4] = {};

    for (int k0 = 0; k0 < K; k0 += 32) {
        #pragma unroll
        for (int it = 0; it < 16; ++it) {
            int f = it * 256 + tid;
            As[f >> 5][f & 31] = f2b(A[(size_t)(row0 + (f >> 5)) * K + (k0 + (f & 31))]);
        }
        #pragma unroll
        for (int it = 0; it < 16; ++it) {
            int f = it * 256 + tid;          // coalesced over cols, transposed write
            Bs[f & 127][f >> 7] = f2b(W[(size_t)(k0 + (f >> 7)) * nper + (ncol0 + (f & 127))]);
        }
        __syncthreads();
        bf16x8 af[4], bfr[4];
        #pragma unroll
        for (int m = 0; m < 4; ++m) af[m]  = *(const bf16x8*)&As[wr + m * 16 + fr][kb];
        #pragma unroll
        for (int n = 0; n < 4; ++n) bfr[n] = *(const bf16x8*)&Bs[wc + n * 16 + fr][kb];
        #pragma unroll
        for (int m = 0; m < 4; ++m)
            #pragma unroll
            for (int n = 0; n < 4; ++n)
                acc[m][n] = __builtin_amdgcn_mfma_f32_16x16x32_bf16(af[m], bfr[n], acc[m][n], 0, 0, 0);
        __syncthreads();
    }

    int rr = (lane >> 4) * 4;
    #pragma unroll
    for (int m = 0; m < 4; ++m) {
        #pragma unroll
        for (int n = 0; n < 4; ++n) {
            int col  = ncol0 + wc + n * 16 + fr;
            float bv = Bv[col];
            #pragma unroll
            for (int ri = 0; ri < 4; ++ri) {
                int row = row0 + wr + m * 16 + rr + ri;
                float val = (acc[m][n][ri] + bv) * alpha;
                if (dogelu) val = gelu_f(val);
                size_t idx = (size_t)row * nper + col;
                if (resid) val += resid[idx];
                out[idx] = val;
            }
        }
    }
}

// ---------------------------------------------------------------------------
// Attention: block per (b, head, 64-row slice). K,V staged to LDS as bf16.
// Bias on the fly: 2*ab + (i>0&&j>0 ? sp*A[h]+C[h] : 0) + ((i==0||j==0)? t :0)
// Per wave: one row at a time; lane = score column (8 cols/lane), full-wave
// shfl softmax, broadcast-P PV.
// ---------------------------------------------------------------------------
__global__ __launch_bounds__(256) void attn_kernel(
    const float* __restrict__ q, const float* __restrict__ k, const float* __restrict__ v,
    const float* __restrict__ ab, const float* __restrict__ sp,
    const float* __restrict__ vd, const float* __restrict__ ac,
    float* __restrict__ o)
{
    __shared__ short ks[512][66];   // pad 66: conflict-free per-row reads
    __shared__ short vs[512][64];   // read per-lane-column: conflict-free unpadded
    __shared__ float qs[4][64];
    __shared__ float ps[4][512];
    int tid = threadIdx.x, lane = tid & 63, w = tid >> 6;
    int blk = blockIdx.x;
    int iq = blk & 7;
    int hh = (blk >> 3) % H;
    int b  = blk / (H * 8);

    for (int it = 0; it < 128; ++it) {
        int f = it * 256 + tid;
        int j = f >> 6, d = f & 63;
        size_t g = ((size_t)(b * S + j) * H + hh) * 64 + d;
        ks[j][d] = f2b(k[g]);
        vs[j][d] = f2b(v[g]);
    }
    __syncthreads();

    float Ah = ac[hh], Ch = ac[16 + hh], th = vd[hh];
    int i0 = iq * 64;
    for (int r = 0; r < 16; ++r) {
        int i = i0 + w * 16 + r;
        qs[w][lane] = q[((size_t)(b * S + i) * H + hh) * 64 + lane];
        __syncthreads();

        float s[8];
        const float* abrow = ab + ((size_t)b * S + i) * S;
        const float* sprow = sp + ((size_t)b * NN + (i - 1)) * NN;  // used only if i>0
        #pragma unroll
        for (int jt = 0; jt < 8; ++jt) {
            int j = jt * 64 + lane;
            float bias = 2.f * abrow[j];
            if (i > 0 && j > 0) bias += sprow[j - 1] * Ah + Ch;
            if (i == 0 || j == 0) bias += th;
            s[jt] = bias;
        }
        for (int d = 0; d < 64; d += 2) {
            float q0 = qs[w][d], q1 = qs[w][d + 1];
            #pragma unroll
            for (int jt = 0; jt < 8; ++jt) {
                uint32_t kk = *(const uint32_t*)&ks[jt * 64 + lane][d];
                s[jt] += q0 * b2f_lo(kk) + q1 * b2f_hi(kk);
            }
        }
        float mx = s[0];
        #pragma unroll
        for (int jt = 1; jt < 8; ++jt) mx = fmaxf(mx, s[jt]);
        #pragma unroll
        for (int off = 1; off < 64; off <<= 1) mx = fmaxf(mx, __shfl_xor(mx, off));
        float p[8];
        float l = 0.f;
        #pragma unroll
        for (int jt = 0; jt < 8; ++jt) { p[jt] = __expf(s[jt] - mx); l += p[jt]; }
        #pragma unroll
        for (int off = 1; off < 64; off <<= 1) l += __shfl_xor(l, off);
        float invl = 1.f / l;
        #pragma unroll
        for (int jt = 0; jt < 8; ++jt) ps[w][jt * 64 + lane] = p[jt] * invl;
        __syncthreads();

        float oa = 0.f;
        #pragma unroll 16
        for (int j = 0; j < 512; ++j) oa += ps[w][j] * b2f(vs[j][lane]);
        o[((size_t)(b * S + i) * H + hh) * 64 + lane] = oa;
    }
}

// ---------------------------------------------------------------------------
extern "C" void kernel_launch(void* const* d_in, const int* in_sizes, int n_in,
                              void* d_out, int out_size, void* d_ws, size_t ws_size,
                              hipStream_t stream)
{
    const float* attn_bias   = (const float*)d_in[0];
    const float* spatial_pos = (const float*)d_in[1];
    const int*   xx          = (const int*)d_in[2];
    const float* node_emb    = (const float*)d_in[3];
    const float* graph_token = (const float*)d_in[4];
    const float* virt_dist   = (const float*)d_in[5];
    const float* sp_w1 = (const float*)d_in[6];
    const float* sp_b1 = (const float*)d_in[7];
    const float* sp_w2 = (const float*)d_in[8];
    const float* sp_b2 = (const float*)d_in[9];
    const float* ln1_s = (const float*)d_in[10];
    const float* ln1_b = (const float*)d_in[11];
    const float* wq = (const float*)d_in[12];
    const float* bq = (const float*)d_in[13];
    const float* wk = (const float*)d_in[14];
    const float* bk = (const float*)d_in[15];
    const float* wv = (const float*)d_in[16];
    const float* bv = (const float*)d_in[17];
    const float* wo = (const float*)d_in[18];
    const float* bo = (const float*)d_in[19];
    const float* ln2_s = (const float*)d_in[20];
    const float* ln2_b = (const float*)d_in[21];
    const float* fw1 = (const float*)d_in[22];
    const float* fb1 = (const float*)d_in[23];
    const float* fw2 = (const float*)d_in[24];
    const float* fb2 = (const float*)d_in[25];
    const float* fln_s = (const float*)d_in[26];
    const float* fln_b = (const float*)d_in[27];

    float* wsf = (float*)d_ws;
    const size_t SZ = (size_t)ROWS * D;       // 3,145,728 floats
    float* h   = wsf;                          // [4096,768]
    float* y   = wsf + SZ;                     // [4096,768]
    float* qb  = wsf + 2 * SZ;                 // q,k,v contiguous [3][4096,768]
    float* ob  = wsf + 5 * SZ;                 // [4096,768]
    float* g   = wsf + 6 * SZ;                 // [4096,3072]
    float* acb = wsf + 10 * SZ;                // A[12],C[12] (32 floats)

    embed_kernel<<<ROWS, 256, 0, stream>>>(xx, node_emb, graph_token, h);
    ac_kernel<<<1, 64, 0, stream>>>(sp_w1, sp_b1, sp_w2, sp_b2, acb);

    for (int l = 0; l < 6; ++l) {
        ln_kernel<<<ROWS, 256, 0, stream>>>(h, ln1_s + l * D, ln1_b + l * D, y);
        // fused QKV: N_total = 2304, which = col-block/768; q scaled by 1/8
        gemm_kernel<<<dim3(32, 18), 256, 0, stream>>>(
            y, wq + (size_t)l * D * D, wk + (size_t)l * D * D, wv + (size_t)l * D * D,
            bq + l * D, bk + l * D, bv + l * D, qb, nullptr, D, D, 0.125f, 0);
        attn_kernel<<<B * H * 8, 256, 0, stream>>>(
            qb, qb + SZ, qb + 2 * SZ, attn_bias, spatial_pos, virt_dist, acb, ob);
        // h = h + o @ wo + bo   (in-place safe: each elem read+written by same thread)
        gemm_kernel<<<dim3(32, 6), 256, 0, stream>>>(
            ob, wo + (size_t)l * D * D, nullptr, nullptr,
            bo + l * D, nullptr, nullptr, h, h, D, D, 1.0f, 0);
        ln_kernel<<<ROWS, 256, 0, stream>>>(h, ln2_s + l * D, ln2_b + l * D, y);
        gemm_kernel<<<dim3(32, 24), 256, 0, stream>>>(
            y, fw1 + (size_t)l * D * FFN, nullptr, nullptr,
            fb1 + l * FFN, nullptr, nullptr, g, nullptr, D, FFN, 1.0f, 1);
        gemm_kernel<<<dim3(32, 6), 256, 0, stream>>>(
            g, fw2 + (size_t)l * FFN * D, nullptr, nullptr,
            fb2 + l * D, nullptr, nullptr, h, h, FFN, D, 1.0f, 0);
    }
    ln_kernel<<<ROWS, 256, 0, stream>>>(h, fln_s, fln_b, (float*)d_out);
}

// Round 3
// 3087.586 us; speedup vs baseline: 2.2390x; 2.2390x over previous
//
#include <hip/hip_runtime.h>
#include <cstdint>
#include <cstddef>

// ---------------------------------------------------------------------------
// Graphormer-ish encoder forward, MI355X (gfx950).
// Round 2: fix mode-1 QKV output stride (ROWS*64 -> ROWS*D). Round 1's MFMA
// attention structure otherwise unchanged.
// ---------------------------------------------------------------------------

typedef __attribute__((ext_vector_type(8))) short bf16x8;
typedef __attribute__((ext_vector_type(4))) short bf16x4;
typedef __attribute__((ext_vector_type(4))) float f32x4;

static constexpr int D    = 768;
static constexpr int H    = 12;
static constexpr int S    = 512;
static constexpr int NN   = 511;
static constexpr int B    = 8;
static constexpr int FFN  = 3072;
static constexpr int ROWS = B * S;   // 4096

__device__ __forceinline__ short f2b(float x) {
    union { float f; uint32_t u; } c; c.f = x;
    uint32_t r = (c.u + 0x7fffu + ((c.u >> 16) & 1u)) >> 16;  // RNE
    return (short)(uint16_t)r;
}
__device__ __forceinline__ float gelu_f(float x) {
    return 0.5f * x * (1.0f + erff(x * 0.7071067811865476f));
}

// ---------------------------------------------------------------------------
// h[b,0,:] = graph_token; h[b,1+n,:] = node_emb[x[b,n,0]]
// ---------------------------------------------------------------------------
__global__ __launch_bounds__(256) void embed_kernel(
    const int* __restrict__ x, const float* __restrict__ emb,
    const float* __restrict__ gtok, float* __restrict__ h)
{
    int row = blockIdx.x;                 // b*S + s
    int b = row >> 9, s = row & (S - 1);
    const float* src = (s == 0) ? gtok : (emb + (size_t)x[b * NN + (s - 1)] * D);
    float* dst = h + (size_t)row * D;
    int t = threadIdx.x;
    dst[t]       = src[t];
    dst[t + 256] = src[t + 256];
    dst[t + 512] = src[t + 512];
}

// ---------------------------------------------------------------------------
// sp-MLP collapses to affine per head: A[h], C[h]
// ---------------------------------------------------------------------------
__global__ void ac_kernel(const float* __restrict__ w1, const float* __restrict__ b1,
                          const float* __restrict__ w2, const float* __restrict__ b2,
                          float* __restrict__ ac)
{
    int h = threadIdx.x;
    if (h < H) {
        float a = 0.f, c = 0.f;
        for (int k = 0; k < 128; ++k) { a += w1[k] * w2[k * H + h]; c += b1[k] * w2[k * H + h]; }
        ac[h] = a; ac[16 + h] = c + b2[h];
    }
}

// ---------------------------------------------------------------------------
// LayerNorm over D=768, one row per block
// ---------------------------------------------------------------------------
__global__ __launch_bounds__(256) void ln_kernel(
    const float* __restrict__ in, const float* __restrict__ sc,
    const float* __restrict__ bi, float* __restrict__ out)
{
    int row = blockIdx.x, t = threadIdx.x;
    const float* x = in + (size_t)row * D;
    float e0 = x[t], e1 = x[t + 256], e2 = x[t + 512];
    float s  = e0 + e1 + e2;
    float sq = e0 * e0 + e1 * e1 + e2 * e2;
    #pragma unroll
    for (int off = 1; off < 64; off <<= 1) { s += __shfl_xor(s, off); sq += __shfl_xor(sq, off); }
    __shared__ float red[8];
    int w = t >> 6, lane = t & 63;
    if (lane == 0) { red[w] = s; red[4 + w] = sq; }
    __syncthreads();
    s  = red[0] + red[1] + red[2] + red[3];
    sq = red[4] + red[5] + red[6] + red[7];
    float m   = s * (1.f / D);
    float inv = rsqrtf(sq * (1.f / D) - m * m + 1e-5f);
    float* o = out + (size_t)row * D;
    o[t]       = (e0 - m) * inv * sc[t]       + bi[t];
    o[t + 256] = (e1 - m) * inv * sc[t + 256] + bi[t + 256];
    o[t + 512] = (e2 - m) * inv * sc[t + 512] + bi[t + 512];
}

// ---------------------------------------------------------------------------
// bf16 MFMA GEMM, 128x128 tile, 4 waves (2x2), 4x4 frags of 16x16x32/wave.
// mode 0: f32 out [row][nper] with optional gelu / residual.
// mode 1: QKV — bf16 out; which 0/1 (q/k) -> [b,h,s,d]; which 2 (v) -> [b,h,d,s].
// ---------------------------------------------------------------------------
__global__ __launch_bounds__(256) void gemm_kernel(
    const float* __restrict__ A,
    const float* __restrict__ W0, const float* __restrict__ W1, const float* __restrict__ W2,
    const float* __restrict__ Bb0, const float* __restrict__ Bb1, const float* __restrict__ Bb2,
    float* __restrict__ outBase, const float* __restrict__ resid,
    short* __restrict__ bfout, int mode,
    int K, int nper, float alpha0, int dogelu)
{
    __shared__ short As[128][40];   // [row][k], +8 pad
    __shared__ short Bs[128][40];   // [col][k] (transposed stage)
    int tid  = threadIdx.x;
    int lane = tid & 63;
    int w    = tid >> 6;
    int row0 = blockIdx.x * 128;
    int n0   = blockIdx.y * 128;
    int which = n0 / nper;
    int ncol0 = n0 - which * nper;
    const float* W  = (which == 0) ? W0  : ((which == 1) ? W1  : W2);
    const float* Bv = (which == 0) ? Bb0 : ((which == 1) ? Bb1 : Bb2);
    float alpha = (which == 0) ? alpha0 : 1.0f;

    int wr = (w >> 1) * 64;
    int wc = (w & 1) * 64;
    int fr = lane & 15;
    int kb = (lane >> 4) * 8;

    f32x4 acc[4][4] = {};

    for (int k0 = 0; k0 < K; k0 += 32) {
        #pragma unroll
        for (int it = 0; it < 16; ++it) {
            int f = it * 256 + tid;
            As[f >> 5][f & 31] = f2b(A[(size_t)(row0 + (f >> 5)) * K + (k0 + (f & 31))]);
        }
        #pragma unroll
        for (int it = 0; it < 16; ++it) {
            int f = it * 256 + tid;
            Bs[f & 127][f >> 7] = f2b(W[(size_t)(k0 + (f >> 7)) * nper + (ncol0 + (f & 127))]);
        }
        __syncthreads();
        bf16x8 af[4], bfr[4];
        #pragma unroll
        for (int m = 0; m < 4; ++m) af[m]  = *(const bf16x8*)&As[wr + m * 16 + fr][kb];
        #pragma unroll
        for (int n = 0; n < 4; ++n) bfr[n] = *(const bf16x8*)&Bs[wc + n * 16 + fr][kb];
        #pragma unroll
        for (int m = 0; m < 4; ++m)
            #pragma unroll
            for (int n = 0; n < 4; ++n)
                acc[m][n] = __builtin_amdgcn_mfma_f32_16x16x32_bf16(af[m], bfr[n], acc[m][n], 0, 0, 0);
        __syncthreads();
    }

    int rr = (lane >> 4) * 4;
    if (mode == 1) {
        // bf16 attention layouts; each tensor occupies ROWS*D shorts
        short* base = bfout + (size_t)which * ROWS * D;
        #pragma unroll
        for (int m = 0; m < 4; ++m) {
            int rowb = row0 + wr + m * 16 + rr;
            int b2 = rowb >> 9, s0 = rowb & 511;
            #pragma unroll
            for (int n = 0; n < 4; ++n) {
                int col = ncol0 + wc + n * 16 + fr;
                int h2 = col >> 6, d2 = col & 63;
                float bv = Bv[col];
                if (which == 2) {
                    bf16x4 pk;
                    #pragma unroll
                    for (int ri = 0; ri < 4; ++ri) pk[ri] = f2b(acc[m][n][ri] + bv);
                    *(bf16x4*)&base[(((size_t)b2 * H + h2) * 64 + d2) * 512 + s0] = pk;
                } else {
                    #pragma unroll
                    for (int ri = 0; ri < 4; ++ri)
                        base[(((size_t)b2 * H + h2) * 512 + (s0 + ri)) * 64 + d2] =
                            f2b((acc[m][n][ri] + bv) * alpha);
                }
            }
        }
        return;
    }

    #pragma unroll
    for (int m = 0; m < 4; ++m) {
        #pragma unroll
        for (int n = 0; n < 4; ++n) {
            int col  = ncol0 + wc + n * 16 + fr;
            float bv = Bv[col];
            #pragma unroll
            for (int ri = 0; ri < 4; ++ri) {
                int row = row0 + wr + m * 16 + rr + ri;
                float val = (acc[m][n][ri] + bv) * alpha;
                if (dogelu) val = gelu_f(val);
                size_t idx = (size_t)row * nper + col;
                if (resid) val += resid[idx];
                outBase[idx] = val;
            }
        }
    }
}

// ---------------------------------------------------------------------------
// MFMA attention. Block = (b, h, 64 q-rows); wave = 16 q-rows.
// Scores: 64 mfma -> s[32] (f32x4). Bias on the fly. Register softmax
// (shfl within 16-lane fr-group). P -> per-wave LDS bf16. PV: 64 mfma with
// V^T fragments straight from global.
// ---------------------------------------------------------------------------
__global__ __launch_bounds__(256) void attn_kernel(
    const short* __restrict__ qb, const short* __restrict__ kbuf,
    const short* __restrict__ vtb,
    const float* __restrict__ ab, const float* __restrict__ sp,
    const float* __restrict__ vd, const float* __restrict__ ac,
    float* __restrict__ o)
{
    __shared__ __align__(16) short pl[4][16][520];   // per-wave P, pad 8
    int tid = threadIdx.x, lane = tid & 63, w = tid >> 6;
    int blk = blockIdx.x;
    int qblk = blk & 7;
    int hh = (blk >> 3) % H;
    int b = blk / (8 * H);
    int fr = lane & 15, g16 = lane >> 4;
    int kb8 = g16 * 8, rr = g16 * 4;
    int i0 = qblk * 64 + w * 16;

    const short* qp = qb   + ((size_t)(b * H + hh) * S) * 64;
    const short* kp = kbuf + ((size_t)(b * H + hh) * S) * 64;
    const short* vp = vtb  + ((size_t)(b * H + hh) * 64) * S;

    bf16x8 aq0 = *(const bf16x8*)&qp[(i0 + fr) * 64 + kb8];
    bf16x8 aq1 = *(const bf16x8*)&qp[(i0 + fr) * 64 + 32 + kb8];

    f32x4 s[32];
    #pragma unroll
    for (int jt = 0; jt < 32; ++jt) {
        bf16x8 kf0 = *(const bf16x8*)&kp[(jt * 16 + fr) * 64 + kb8];
        bf16x8 kf1 = *(const bf16x8*)&kp[(jt * 16 + fr) * 64 + 32 + kb8];
        f32x4 a = {};
        a = __builtin_amdgcn_mfma_f32_16x16x32_bf16(aq0, kf0, a, 0, 0, 0);
        s[jt] = __builtin_amdgcn_mfma_f32_16x16x32_bf16(aq1, kf1, a, 0, 0, 0);
    }

    // bias: 2*ab + [i>0&&j>0] (sp*A + C) + [i==0||j==0] t
    float Ah = ac[hh], Ch = ac[16 + hh], th = vd[hh];
    const float* abb = ab + (size_t)b * S * S;
    const float* spb = sp + (size_t)b * NN * NN;
    #pragma unroll
    for (int jt = 0; jt < 32; ++jt) {
        int j = jt * 16 + fr;
        #pragma unroll
        for (int ri = 0; ri < 4; ++ri) {
            int i = i0 + rr + ri;
            float bias = 2.f * abb[(size_t)i * S + j];
            if (i > 0 && j > 0) bias += spb[(size_t)(i - 1) * NN + (j - 1)] * Ah + Ch;
            if (i == 0 || j == 0) bias += th;
            s[jt][ri] += bias;
        }
    }

    // softmax per row (row spread over the 16 lanes of this fr-group)
    float invl[4];
    #pragma unroll
    for (int ri = 0; ri < 4; ++ri) {
        float mx = s[0][ri];
        #pragma unroll
        for (int jt = 1; jt < 32; ++jt) mx = fmaxf(mx, s[jt][ri]);
        mx = fmaxf(mx, __shfl_xor(mx, 1));
        mx = fmaxf(mx, __shfl_xor(mx, 2));
        mx = fmaxf(mx, __shfl_xor(mx, 4));
        mx = fmaxf(mx, __shfl_xor(mx, 8));
        float l = 0.f;
        #pragma unroll
        for (int jt = 0; jt < 32; ++jt) { float p = __expf(s[jt][ri] - mx); s[jt][ri] = p; l += p; }
        l += __shfl_xor(l, 1); l += __shfl_xor(l, 2);
        l += __shfl_xor(l, 4); l += __shfl_xor(l, 8);
        invl[ri] = 1.f / l;
    }

    // P -> LDS (unnormalized; 1/l applied to O)
    #pragma unroll
    for (int jt = 0; jt < 32; ++jt)
        #pragma unroll
        for (int ri = 0; ri < 4; ++ri)
            pl[w][rr + ri][jt * 16 + fr] = f2b(s[jt][ri]);

    // PV (wave-local LDS: no barrier needed)
    f32x4 oacc[4] = {};
    #pragma unroll
    for (int jt2 = 0; jt2 < 16; ++jt2) {
        bf16x8 pa = *(const bf16x8*)&pl[w][fr][jt2 * 32 + kb8];
        #pragma unroll
        for (int dt = 0; dt < 4; ++dt) {
            bf16x8 pb = *(const bf16x8*)&vp[(dt * 16 + fr) * S + jt2 * 32 + kb8];
            oacc[dt] = __builtin_amdgcn_mfma_f32_16x16x32_bf16(pa, pb, oacc[dt], 0, 0, 0);
        }
    }
    #pragma unroll
    for (int dt = 0; dt < 4; ++dt)
        #pragma unroll
        for (int ri = 0; ri < 4; ++ri)
            o[((size_t)(b * S + i0 + rr + ri) * H + hh) * 64 + dt * 16 + fr] = oacc[dt][ri] * invl[ri];
}

// ---------------------------------------------------------------------------
extern "C" void kernel_launch(void* const* d_in, const int* in_sizes, int n_in,
                              void* d_out, int out_size, void* d_ws, size_t ws_size,
                              hipStream_t stream)
{
    const float* attn_bias   = (const float*)d_in[0];
    const float* spatial_pos = (const float*)d_in[1];
    const int*   xx          = (const int*)d_in[2];
    const float* node_emb    = (const float*)d_in[3];
    const float* graph_token = (const float*)d_in[4];
    const float* virt_dist   = (const float*)d_in[5];
    const float* sp_w1 = (const float*)d_in[6];
    const float* sp_b1 = (const float*)d_in[7];
    const float* sp_w2 = (const float*)d_in[8];
    const float* sp_b2 = (const float*)d_in[9];
    const float* ln1_s = (const float*)d_in[10];
    const float* ln1_b = (const float*)d_in[11];
    const float* wq = (const float*)d_in[12];
    const float* bq = (const float*)d_in[13];
    const float* wk = (const float*)d_in[14];
    const float* bk = (const float*)d_in[15];
    const float* wv = (const float*)d_in[16];
    const float* bv = (const float*)d_in[17];
    const float* wo = (const float*)d_in[18];
    const float* bo = (const float*)d_in[19];
    const float* ln2_s = (const float*)d_in[20];
    const float* ln2_b = (const float*)d_in[21];
    const float* fw1 = (const float*)d_in[22];
    const float* fb1 = (const float*)d_in[23];
    const float* fw2 = (const float*)d_in[24];
    const float* fb2 = (const float*)d_in[25];
    const float* fln_s = (const float*)d_in[26];
    const float* fln_b = (const float*)d_in[27];

    float* wsf = (float*)d_ws;
    const size_t SZ = (size_t)ROWS * D;        // 3,145,728 floats
    float* h   = wsf;                          // [4096,768]
    float* y   = wsf + SZ;                     // [4096,768]
    float* ob  = wsf + 2 * SZ;                 // [4096,768]
    float* g   = wsf + 3 * SZ;                 // [4096,3072]
    float* acb = wsf + 7 * SZ;                 // A[12],C[12]
    short* bfq = (short*)(wsf + 7 * SZ + 64);  // 3 x [ROWS*D] bf16 (q,k,v^T)

    embed_kernel<<<ROWS, 256, 0, stream>>>(xx, node_emb, graph_token, h);
    ac_kernel<<<1, 64, 0, stream>>>(sp_w1, sp_b1, sp_w2, sp_b2, acb);

    for (int l = 0; l < 6; ++l) {
        ln_kernel<<<ROWS, 256, 0, stream>>>(h, ln1_s + l * D, ln1_b + l * D, y);
        gemm_kernel<<<dim3(32, 18), 256, 0, stream>>>(
            y, wq + (size_t)l * D * D, wk + (size_t)l * D * D, wv + (size_t)l * D * D,
            bq + l * D, bk + l * D, bv + l * D, nullptr, nullptr,
            bfq, 1, D, D, 0.125f, 0);
        attn_kernel<<<B * H * 8, 256, 0, stream>>>(
            bfq, bfq + SZ, bfq + 2 * SZ, attn_bias, spatial_pos, virt_dist, acb, ob);
        gemm_kernel<<<dim3(32, 6), 256, 0, stream>>>(
            ob, wo + (size_t)l * D * D, nullptr, nullptr,
            bo + l * D, nullptr, nullptr, h, h, nullptr, 0, D, D, 1.0f, 0);
        ln_kernel<<<ROWS, 256, 0, stream>>>(h, ln2_s + l * D, ln2_b + l * D, y);
        gemm_kernel<<<dim3(32, 24), 256, 0, stream>>>(
            y, fw1 + (size_t)l * D * FFN, nullptr, nullptr,
            fb1 + l * FFN, nullptr, nullptr, g, nullptr, nullptr, 0, D, FFN, 1.0f, 1);
        gemm_kernel<<<dim3(32, 6), 256, 0, stream>>>(
            g, fw2 + (size_t)l * FFN * D, nullptr, nullptr,
            fb2 + l * D, nullptr, nullptr, h, h, nullptr, 0, FFN, D, 1.0f, 0);
    }
    ln_kernel<<<ROWS, 256, 0, stream>>>(h, fln_s, fln_b, (float*)d_out);
}

// Round 4
// 1980.500 us; speedup vs baseline: 3.4905x; 1.5590x over previous
//
#include <hip/hip_runtime.h>
#include <cstdint>
#include <cstddef>

// ---------------------------------------------------------------------------
// Graphormer-ish encoder forward, MI355X (gfx950).
// Round 3: all-bf16 GEMM pipeline. Per-layer weight f32->bf16 transpose
// pre-pass; LN/attn/FFN1 emit bf16 activations; GEMM stages both operands
// with global_load_lds width=16 (no VALU staging, no f32->bf16 in GEMM).
// ---------------------------------------------------------------------------

typedef __attribute__((ext_vector_type(8))) short bf16x8;
typedef __attribute__((ext_vector_type(4))) short bf16x4;
typedef __attribute__((ext_vector_type(4))) float f32x4;

static constexpr int D    = 768;
static constexpr int H    = 12;
static constexpr int S    = 512;
static constexpr int NN   = 511;
static constexpr int B    = 8;
static constexpr int FFN  = 3072;
static constexpr int ROWS = B * S;   // 4096

__device__ __forceinline__ short f2b(float x) {
    union { float f; uint32_t u; } c; c.f = x;
    uint32_t r = (c.u + 0x7fffu + ((c.u >> 16) & 1u)) >> 16;  // RNE
    return (short)(uint16_t)r;
}
__device__ __forceinline__ float gelu_f(float x) {
    return 0.5f * x * (1.0f + erff(x * 0.7071067811865476f));
}
__device__ __forceinline__ void gload16(const void* g, void* l) {
    __builtin_amdgcn_global_load_lds(
        (const __attribute__((address_space(1))) void*)g,
        (__attribute__((address_space(3))) void*)l, 16, 0, 0);
}

// ---------------------------------------------------------------------------
// h[b,0,:] = graph_token; h[b,1+n,:] = node_emb[x[b,n,0]]
// ---------------------------------------------------------------------------
__global__ __launch_bounds__(256) void embed_kernel(
    const int* __restrict__ x, const float* __restrict__ emb,
    const float* __restrict__ gtok, float* __restrict__ h)
{
    int row = blockIdx.x;
    int b = row >> 9, s = row & (S - 1);
    const float* src = (s == 0) ? gtok : (emb + (size_t)x[b * NN + (s - 1)] * D);
    float* dst = h + (size_t)row * D;
    int t = threadIdx.x;
    dst[t]       = src[t];
    dst[t + 256] = src[t + 256];
    dst[t + 512] = src[t + 512];
}

// ---------------------------------------------------------------------------
// sp-MLP collapses to affine per head: A[h], C[h]
// ---------------------------------------------------------------------------
__global__ void ac_kernel(const float* __restrict__ w1, const float* __restrict__ b1,
                          const float* __restrict__ w2, const float* __restrict__ b2,
                          float* __restrict__ ac)
{
    int h = threadIdx.x;
    if (h < H) {
        float a = 0.f, c = 0.f;
        for (int k = 0; k < 128; ++k) { a += w1[k] * w2[k * H + h]; c += b1[k] * w2[k * H + h]; }
        ac[h] = a; ac[16 + h] = c + b2[h];
    }
}

// ---------------------------------------------------------------------------
// Per-layer weight convert+transpose: f32 [R][C] -> bf16 [C][R].
// 64x64 tiles via LDS [64][65] (2-way max on transposed read = free).
// grid.x = 1728 tiles: [0,432) wq/wk/wv -> packed wqkvT [2304][768];
// [432,576) wo; [576,1152) fw1 [768][3072]->[3072][768];
// [1152,1728) fw2 [3072][768]->[768][3072].
// ---------------------------------------------------------------------------
__global__ __launch_bounds__(256) void wcvt_kernel(
    const float* __restrict__ wq, const float* __restrict__ wk,
    const float* __restrict__ wv, const float* __restrict__ wo,
    const float* __restrict__ f1, const float* __restrict__ f2,
    short* __restrict__ wqkvT, short* __restrict__ woT,
    short* __restrict__ f1T, short* __restrict__ f2T)
{
    int t = blockIdx.x;
    const float* in; short* out; int R, C, tr, tc;
    if (t < 432) {
        int which = t / 144, tt = t - which * 144;
        in = (which == 0) ? wq : ((which == 1) ? wk : wv);
        out = wqkvT + (size_t)which * 768 * 768;
        R = 768; C = 768; tr = tt / 12; tc = tt % 12;
    } else if (t < 576) {
        int tt = t - 432; in = wo; out = woT; R = 768; C = 768; tr = tt / 12; tc = tt % 12;
    } else if (t < 1152) {
        int tt = t - 576; in = f1; out = f1T; R = 768; C = 3072; tr = tt / 48; tc = tt % 48;
    } else {
        int tt = t - 1152; in = f2; out = f2T; R = 3072; C = 768; tr = tt / 12; tc = tt % 12;
    }
    int r0 = tr * 64, c0 = tc * 64;
    __shared__ short tile[64][65];
    int tid = threadIdx.x;
    #pragma unroll
    for (int i = 0; i < 16; ++i) {
        int e = i * 256 + tid; int r = e >> 6, c = e & 63;
        tile[r][c] = f2b(in[(size_t)(r0 + r) * C + c0 + c]);
    }
    __syncthreads();
    #pragma unroll
    for (int i = 0; i < 16; ++i) {
        int e = i * 256 + tid; int c = e >> 6, r = e & 63;
        out[(size_t)(c0 + c) * R + r0 + r] = tile[r][c];
    }
}

// ---------------------------------------------------------------------------
// LayerNorm over D=768; outputs f32 (outF) or bf16 (outB), whichever non-null
// ---------------------------------------------------------------------------
__global__ __launch_bounds__(256) void ln_kernel(
    const float* __restrict__ in, const float* __restrict__ sc,
    const float* __restrict__ bi, float* __restrict__ outF,
    short* __restrict__ outB)
{
    int row = blockIdx.x, t = threadIdx.x;
    const float* x = in + (size_t)row * D;
    float e0 = x[t], e1 = x[t + 256], e2 = x[t + 512];
    float s  = e0 + e1 + e2;
    float sq = e0 * e0 + e1 * e1 + e2 * e2;
    #pragma unroll
    for (int off = 1; off < 64; off <<= 1) { s += __shfl_xor(s, off); sq += __shfl_xor(sq, off); }
    __shared__ float red[8];
    int w = t >> 6, lane = t & 63;
    if (lane == 0) { red[w] = s; red[4 + w] = sq; }
    __syncthreads();
    s  = red[0] + red[1] + red[2] + red[3];
    sq = red[4] + red[5] + red[6] + red[7];
    float m   = s * (1.f / D);
    float inv = rsqrtf(sq * (1.f / D) - m * m + 1e-5f);
    float v0 = (e0 - m) * inv * sc[t]       + bi[t];
    float v1 = (e1 - m) * inv * sc[t + 256] + bi[t + 256];
    float v2 = (e2 - m) * inv * sc[t + 512] + bi[t + 512];
    if (outB) {
        short* o = outB + (size_t)row * D;
        o[t] = f2b(v0); o[t + 256] = f2b(v1); o[t + 512] = f2b(v2);
    } else {
        float* o = outF + (size_t)row * D;
        o[t] = v0; o[t + 256] = v1; o[t + 512] = v2;
    }
}

// ---------------------------------------------------------------------------
// bf16 MFMA GEMM with global_load_lds staging. A [M][K] bf16, Wt [Ntot][K]
// bf16 (pre-transposed). 128x128 tile, 4 waves (2x2), 4x4 frags 16x16x32.
// mode 0: f32 out [M][nper] + resid.   mode 1: QKV bf16 layouts (q scaled).
// mode 2: bf16 out [M][nper] with gelu (FFN1).
// ---------------------------------------------------------------------------
__global__ __launch_bounds__(256) void gemm_bf(
    const short* __restrict__ A, const short* __restrict__ Wt,
    const float* __restrict__ Bb0, const float* __restrict__ Bb1, const float* __restrict__ Bb2,
    float* __restrict__ outF, const float* __restrict__ resid,
    short* __restrict__ outB,
    int K, int nper, float alpha0, int mode)
{
    __shared__ __align__(16) short As[128 * 32];
    __shared__ __align__(16) short Bs[128 * 32];
    int tid  = threadIdx.x;
    int lane = tid & 63;
    int w    = tid >> 6;
    int row0 = blockIdx.x * 128;
    int n0   = blockIdx.y * 128;
    int which = n0 / nper;
    int ncol0 = n0 - which * nper;
    const float* Bv = (which == 0) ? Bb0 : ((which == 1) ? Bb1 : Bb2);
    float alpha = (which == 0) ? alpha0 : 1.0f;

    int wr = (w >> 1) * 64;
    int wc = (w & 1) * 64;
    int fr = lane & 15;
    int kb8 = (lane >> 4) * 8;

    // staging: per-lane 16B (8 bf16 along k); t' = i*256+tid -> r=t'/4, kk=(t'&3)*8
    int sr = tid >> 2, skk = (tid & 3) * 8;

    f32x4 acc[4][4] = {};

    for (int k0 = 0; k0 < K; k0 += 32) {
        #pragma unroll
        for (int i = 0; i < 2; ++i) {
            int r = i * 64 + sr;
            gload16(A  + (size_t)(row0 + r) * K + k0 + skk,
                    (char*)As + ((size_t)i * 256 + w * 64) * 16);
            gload16(Wt + (size_t)(n0 + r) * K + k0 + skk,
                    (char*)Bs + ((size_t)i * 256 + w * 64) * 16);
        }
        __syncthreads();
        bf16x8 af[4], bfr[4];
        #pragma unroll
        for (int m = 0; m < 4; ++m) af[m]  = *(const bf16x8*)&As[(wr + m * 16 + fr) * 32 + kb8];
        #pragma unroll
        for (int n = 0; n < 4; ++n) bfr[n] = *(const bf16x8*)&Bs[(wc + n * 16 + fr) * 32 + kb8];
        #pragma unroll
        for (int m = 0; m < 4; ++m)
            #pragma unroll
            for (int n = 0; n < 4; ++n)
                acc[m][n] = __builtin_amdgcn_mfma_f32_16x16x32_bf16(af[m], bfr[n], acc[m][n], 0, 0, 0);
        __syncthreads();
    }

    int rr = (lane >> 4) * 4;
    if (mode == 1) {
        short* base = outB + (size_t)which * ROWS * D;
        #pragma unroll
        for (int m = 0; m < 4; ++m) {
            int rowb = row0 + wr + m * 16 + rr;
            int b2 = rowb >> 9, s0 = rowb & 511;
            #pragma unroll
            for (int n = 0; n < 4; ++n) {
                int col = ncol0 + wc + n * 16 + fr;
                int h2 = col >> 6, d2 = col & 63;
                float bv = Bv[col];
                if (which == 2) {
                    bf16x4 pk;
                    #pragma unroll
                    for (int ri = 0; ri < 4; ++ri) pk[ri] = f2b(acc[m][n][ri] + bv);
                    *(bf16x4*)&base[(((size_t)b2 * H + h2) * 64 + d2) * 512 + s0] = pk;
                } else {
                    #pragma unroll
                    for (int ri = 0; ri < 4; ++ri)
                        base[(((size_t)b2 * H + h2) * 512 + (s0 + ri)) * 64 + d2] =
                            f2b((acc[m][n][ri] + bv) * alpha);
                }
            }
        }
        return;
    }

    #pragma unroll
    for (int m = 0; m < 4; ++m) {
        #pragma unroll
        for (int n = 0; n < 4; ++n) {
            int col  = ncol0 + wc + n * 16 + fr;
            float bv = Bv[col];
            #pragma unroll
            for (int ri = 0; ri < 4; ++ri) {
                int row = row0 + wr + m * 16 + rr + ri;
                size_t idx = (size_t)row * nper + col;
                float val = acc[m][n][ri] + bv;
                if (mode == 2) {
                    outB[idx] = f2b(gelu_f(val));
                } else {
                    outF[idx] = val + resid[idx];
                }
            }
        }
    }
}

// ---------------------------------------------------------------------------
// MFMA attention (round-2 structure); output now bf16.
// ---------------------------------------------------------------------------
__global__ __launch_bounds__(256) void attn_kernel(
    const short* __restrict__ qb, const short* __restrict__ kbuf,
    const short* __restrict__ vtb,
    const float* __restrict__ ab, const float* __restrict__ sp,
    const float* __restrict__ vd, const float* __restrict__ ac,
    short* __restrict__ o)
{
    __shared__ __align__(16) short pl[4][16][520];
    int tid = threadIdx.x, lane = tid & 63, w = tid >> 6;
    int blk = blockIdx.x;
    int qblk = blk & 7;
    int hh = (blk >> 3) % H;
    int b = blk / (8 * H);
    int fr = lane & 15, g16 = lane >> 4;
    int kb8 = g16 * 8, rr = g16 * 4;
    int i0 = qblk * 64 + w * 16;

    const short* qp = qb   + ((size_t)(b * H + hh) * S) * 64;
    const short* kp = kbuf + ((size_t)(b * H + hh) * S) * 64;
    const short* vp = vtb  + ((size_t)(b * H + hh) * 64) * S;

    bf16x8 aq0 = *(const bf16x8*)&qp[(i0 + fr) * 64 + kb8];
    bf16x8 aq1 = *(const bf16x8*)&qp[(i0 + fr) * 64 + 32 + kb8];

    f32x4 s[32];
    #pragma unroll
    for (int jt = 0; jt < 32; ++jt) {
        bf16x8 kf0 = *(const bf16x8*)&kp[(jt * 16 + fr) * 64 + kb8];
        bf16x8 kf1 = *(const bf16x8*)&kp[(jt * 16 + fr) * 64 + 32 + kb8];
        f32x4 a = {};
        a = __builtin_amdgcn_mfma_f32_16x16x32_bf16(aq0, kf0, a, 0, 0, 0);
        s[jt] = __builtin_amdgcn_mfma_f32_16x16x32_bf16(aq1, kf1, a, 0, 0, 0);
    }

    float Ah = ac[hh], Ch = ac[16 + hh], th = vd[hh];
    const float* abb = ab + (size_t)b * S * S;
    const float* spb = sp + (size_t)b * NN * NN;
    #pragma unroll
    for (int jt = 0; jt < 32; ++jt) {
        int j = jt * 16 + fr;
        #pragma unroll
        for (int ri = 0; ri < 4; ++ri) {
            int i = i0 + rr + ri;
            float bias = 2.f * abb[(size_t)i * S + j];
            if (i > 0 && j > 0) bias += spb[(size_t)(i - 1) * NN + (j - 1)] * Ah + Ch;
            if (i == 0 || j == 0) bias += th;
            s[jt][ri] += bias;
        }
    }

    float invl[4];
    #pragma unroll
    for (int ri = 0; ri < 4; ++ri) {
        float mx = s[0][ri];
        #pragma unroll
        for (int jt = 1; jt < 32; ++jt) mx = fmaxf(mx, s[jt][ri]);
        mx = fmaxf(mx, __shfl_xor(mx, 1));
        mx = fmaxf(mx, __shfl_xor(mx, 2));
        mx = fmaxf(mx, __shfl_xor(mx, 4));
        mx = fmaxf(mx, __shfl_xor(mx, 8));
        float l = 0.f;
        #pragma unroll
        for (int jt = 0; jt < 32; ++jt) { float p = __expf(s[jt][ri] - mx); s[jt][ri] = p; l += p; }
        l += __shfl_xor(l, 1); l += __shfl_xor(l, 2);
        l += __shfl_xor(l, 4); l += __shfl_xor(l, 8);
        invl[ri] = 1.f / l;
    }

    #pragma unroll
    for (int jt = 0; jt < 32; ++jt)
        #pragma unroll
        for (int ri = 0; ri < 4; ++ri)
            pl[w][rr + ri][jt * 16 + fr] = f2b(s[jt][ri]);

    f32x4 oacc[4] = {};
    #pragma unroll
    for (int jt2 = 0; jt2 < 16; ++jt2) {
        bf16x8 pa = *(const bf16x8*)&pl[w][fr][jt2 * 32 + kb8];
        #pragma unroll
        for (int dt = 0; dt < 4; ++dt) {
            bf16x8 pb = *(const bf16x8*)&vp[(dt * 16 + fr) * S + jt2 * 32 + kb8];
            oacc[dt] = __builtin_amdgcn_mfma_f32_16x16x32_bf16(pa, pb, oacc[dt], 0, 0, 0);
        }
    }
    #pragma unroll
    for (int dt = 0; dt < 4; ++dt)
        #pragma unroll
        for (int ri = 0; ri < 4; ++ri)
            o[((size_t)(b * S + i0 + rr + ri) * H + hh) * 64 + dt * 16 + fr] = f2b(oacc[dt][ri] * invl[ri]);
}

// ---------------------------------------------------------------------------
extern "C" void kernel_launch(void* const* d_in, const int* in_sizes, int n_in,
                              void* d_out, int out_size, void* d_ws, size_t ws_size,
                              hipStream_t stream)
{
    const float* attn_bias   = (const float*)d_in[0];
    const float* spatial_pos = (const float*)d_in[1];
    const int*   xx          = (const int*)d_in[2];
    const float* node_emb    = (const float*)d_in[3];
    const float* graph_token = (const float*)d_in[4];
    const float* virt_dist   = (const float*)d_in[5];
    const float* sp_w1 = (const float*)d_in[6];
    const float* sp_b1 = (const float*)d_in[7];
    const float* sp_w2 = (const float*)d_in[8];
    const float* sp_b2 = (const float*)d_in[9];
    const float* ln1_s = (const float*)d_in[10];
    const float* ln1_b = (const float*)d_in[11];
    const float* wq = (const float*)d_in[12];
    const float* bq = (const float*)d_in[13];
    const float* wk = (const float*)d_in[14];
    const float* bk = (const float*)d_in[15];
    const float* wv = (const float*)d_in[16];
    const float* bv = (const float*)d_in[17];
    const float* wo = (const float*)d_in[18];
    const float* bo = (const float*)d_in[19];
    const float* ln2_s = (const float*)d_in[20];
    const float* ln2_b = (const float*)d_in[21];
    const float* fw1 = (const float*)d_in[22];
    const float* fb1 = (const float*)d_in[23];
    const float* fw2 = (const float*)d_in[24];
    const float* fb2 = (const float*)d_in[25];
    const float* fln_s = (const float*)d_in[26];
    const float* fln_b = (const float*)d_in[27];

    float* wsf = (float*)d_ws;
    const size_t SZ = (size_t)ROWS * D;        // 3,145,728
    float* h   = wsf;                          // f32 [ROWS][D]
    float* acb = wsf + SZ;                     // A[12],C[12]
    short* s16 = (short*)(wsf + SZ + 64);
    short* yob = s16;                          // bf16 [ROWS][D]  (y / attn-out shared)
    short* g16 = s16 + SZ;                     // bf16 [ROWS][FFN]
    short* bfq = g16 + (size_t)ROWS * FFN;     // 3 x bf16 [ROWS*D] (q,k,v^T)
    short* wqkvT = bfq + 3 * SZ;               // [2304][768]
    short* woT   = wqkvT + 2304 * 768;         // [768][768]
    short* f1T   = woT + 768 * 768;            // [3072][768]
    short* f2T   = f1T + (size_t)3072 * 768;   // [768][3072]

    embed_kernel<<<ROWS, 256, 0, stream>>>(xx, node_emb, graph_token, h);
    ac_kernel<<<1, 64, 0, stream>>>(sp_w1, sp_b1, sp_w2, sp_b2, acb);

    for (int l = 0; l < 6; ++l) {
        wcvt_kernel<<<1728, 256, 0, stream>>>(
            wq + (size_t)l * D * D, wk + (size_t)l * D * D, wv + (size_t)l * D * D,
            wo + (size_t)l * D * D, fw1 + (size_t)l * D * FFN, fw2 + (size_t)l * FFN * D,
            wqkvT, woT, f1T, f2T);
        ln_kernel<<<ROWS, 256, 0, stream>>>(h, ln1_s + l * D, ln1_b + l * D, nullptr, yob);
        gemm_bf<<<dim3(32, 18), 256, 0, stream>>>(
            yob, wqkvT, bq + l * D, bk + l * D, bv + l * D,
            nullptr, nullptr, bfq, D, D, 0.125f, 1);
        attn_kernel<<<B * H * 8, 256, 0, stream>>>(
            bfq, bfq + SZ, bfq + 2 * SZ, attn_bias, spatial_pos, virt_dist, acb, yob);
        gemm_bf<<<dim3(32, 6), 256, 0, stream>>>(
            yob, woT, bo + l * D, nullptr, nullptr,
            h, h, nullptr, D, D, 1.0f, 0);
        ln_kernel<<<ROWS, 256, 0, stream>>>(h, ln2_s + l * D, ln2_b + l * D, nullptr, yob);
        gemm_bf<<<dim3(32, 24), 256, 0, stream>>>(
            yob, f1T, fb1 + l * FFN, nullptr, nullptr,
            nullptr, nullptr, g16, D, FFN, 1.0f, 2);
        gemm_bf<<<dim3(32, 6), 256, 0, stream>>>(
            g16, f2T, fb2 + l * D, nullptr, nullptr,
            h, h, nullptr, FFN, D, 1.0f, 0);
    }
    ln_kernel<<<ROWS, 256, 0, stream>>>(h, fln_s, fln_b, (float*)d_out, nullptr);
}

// Round 5
// 1662.370 us; speedup vs baseline: 4.1585x; 1.1914x over previous
//
#include <hip/hip_runtime.h>
#include <cstdint>
#include <cstddef>

// ---------------------------------------------------------------------------
// Graphormer-ish encoder forward, MI355X (gfx950).
// Round 4: attention de-latencification. (1) bias pre-packed once into a
// bf16x2 [B][S][S] tensor (2*ab, sp) -> one u32 load per score instead of two
// f32 gathers; (2) XCD-aware attn block swizzle (batch == XCD) so K/V and
// bias are per-XCD L2-resident.
// ---------------------------------------------------------------------------

typedef __attribute__((ext_vector_type(8))) short bf16x8;
typedef __attribute__((ext_vector_type(4))) short bf16x4;
typedef __attribute__((ext_vector_type(4))) float f32x4;

static constexpr int D    = 768;
static constexpr int H    = 12;
static constexpr int S    = 512;
static constexpr int NN   = 511;
static constexpr int B    = 8;
static constexpr int FFN  = 3072;
static constexpr int ROWS = B * S;   // 4096

__device__ __forceinline__ short f2b(float x) {
    union { float f; uint32_t u; } c; c.f = x;
    uint32_t r = (c.u + 0x7fffu + ((c.u >> 16) & 1u)) >> 16;  // RNE
    return (short)(uint16_t)r;
}
__device__ __forceinline__ float b2f_lo(uint32_t u) {
    union { uint32_t u; float f; } c; c.u = u << 16; return c.f;
}
__device__ __forceinline__ float b2f_hi(uint32_t u) {
    union { uint32_t u; float f; } c; c.u = u & 0xffff0000u; return c.f;
}
__device__ __forceinline__ float gelu_f(float x) {
    return 0.5f * x * (1.0f + erff(x * 0.7071067811865476f));
}
__device__ __forceinline__ void gload16(const void* g, void* l) {
    __builtin_amdgcn_global_load_lds(
        (const __attribute__((address_space(1))) void*)g,
        (__attribute__((address_space(3))) void*)l, 16, 0, 0);
}

// ---------------------------------------------------------------------------
// h[b,0,:] = graph_token; h[b,1+n,:] = node_emb[x[b,n,0]]
// ---------------------------------------------------------------------------
__global__ __launch_bounds__(256) void embed_kernel(
    const int* __restrict__ x, const float* __restrict__ emb,
    const float* __restrict__ gtok, float* __restrict__ h)
{
    int row = blockIdx.x;
    int b = row >> 9, s = row & (S - 1);
    const float* src = (s == 0) ? gtok : (emb + (size_t)x[b * NN + (s - 1)] * D);
    float* dst = h + (size_t)row * D;
    int t = threadIdx.x;
    dst[t]       = src[t];
    dst[t + 256] = src[t + 256];
    dst[t + 512] = src[t + 512];
}

// ---------------------------------------------------------------------------
// sp-MLP collapses to affine per head: A[h], C[h]
// ---------------------------------------------------------------------------
__global__ void ac_kernel(const float* __restrict__ w1, const float* __restrict__ b1,
                          const float* __restrict__ w2, const float* __restrict__ b2,
                          float* __restrict__ ac)
{
    int h = threadIdx.x;
    if (h < H) {
        float a = 0.f, c = 0.f;
        for (int k = 0; k < 128; ++k) { a += w1[k] * w2[k * H + h]; c += b1[k] * w2[k * H + h]; }
        ac[h] = a; ac[16 + h] = c + b2[h];
    }
}

// ---------------------------------------------------------------------------
// Pack bias inputs once: pb[b,i,j] = u32( bf16(2*ab) | bf16(sp_interior)<<16 )
// ---------------------------------------------------------------------------
__global__ __launch_bounds__(256) void bias_pack_kernel(
    const float* __restrict__ ab, const float* __restrict__ sp,
    uint32_t* __restrict__ pb)
{
    int row = blockIdx.x;                 // b*S + i
    int b = row >> 9, i = row & 511;
    const float* abr = ab + (size_t)row * S;
    const float* spr = sp + ((size_t)b * NN + (i - 1)) * NN;
    uint32_t* out = pb + (size_t)row * S;
    #pragma unroll
    for (int jt = 0; jt < 2; ++jt) {
        int j = jt * 256 + threadIdx.x;
        float a2 = 2.f * abr[j];
        float spv = (i > 0 && j > 0) ? spr[j - 1] : 0.f;
        out[j] = (uint32_t)(uint16_t)f2b(a2) | ((uint32_t)(uint16_t)f2b(spv) << 16);
    }
}

// ---------------------------------------------------------------------------
// Per-layer weight convert+transpose: f32 [R][C] -> bf16 [C][R].
// ---------------------------------------------------------------------------
__global__ __launch_bounds__(256) void wcvt_kernel(
    const float* __restrict__ wq, const float* __restrict__ wk,
    const float* __restrict__ wv, const float* __restrict__ wo,
    const float* __restrict__ f1, const float* __restrict__ f2,
    short* __restrict__ wqkvT, short* __restrict__ woT,
    short* __restrict__ f1T, short* __restrict__ f2T)
{
    int t = blockIdx.x;
    const float* in; short* out; int R, C, tr, tc;
    if (t < 432) {
        int which = t / 144, tt = t - which * 144;
        in = (which == 0) ? wq : ((which == 1) ? wk : wv);
        out = wqkvT + (size_t)which * 768 * 768;
        R = 768; C = 768; tr = tt / 12; tc = tt % 12;
    } else if (t < 576) {
        int tt = t - 432; in = wo; out = woT; R = 768; C = 768; tr = tt / 12; tc = tt % 12;
    } else if (t < 1152) {
        int tt = t - 576; in = f1; out = f1T; R = 768; C = 3072; tr = tt / 48; tc = tt % 48;
    } else {
        int tt = t - 1152; in = f2; out = f2T; R = 3072; C = 768; tr = tt / 12; tc = tt % 12;
    }
    int r0 = tr * 64, c0 = tc * 64;
    __shared__ short tile[64][65];
    int tid = threadIdx.x;
    #pragma unroll
    for (int i = 0; i < 16; ++i) {
        int e = i * 256 + tid; int r = e >> 6, c = e & 63;
        tile[r][c] = f2b(in[(size_t)(r0 + r) * C + c0 + c]);
    }
    __syncthreads();
    #pragma unroll
    for (int i = 0; i < 16; ++i) {
        int e = i * 256 + tid; int c = e >> 6, r = e & 63;
        out[(size_t)(c0 + c) * R + r0 + r] = tile[r][c];
    }
}

// ---------------------------------------------------------------------------
// LayerNorm over D=768; outputs f32 (outF) or bf16 (outB), whichever non-null
// ---------------------------------------------------------------------------
__global__ __launch_bounds__(256) void ln_kernel(
    const float* __restrict__ in, const float* __restrict__ sc,
    const float* __restrict__ bi, float* __restrict__ outF,
    short* __restrict__ outB)
{
    int row = blockIdx.x, t = threadIdx.x;
    const float* x = in + (size_t)row * D;
    float e0 = x[t], e1 = x[t + 256], e2 = x[t + 512];
    float s  = e0 + e1 + e2;
    float sq = e0 * e0 + e1 * e1 + e2 * e2;
    #pragma unroll
    for (int off = 1; off < 64; off <<= 1) { s += __shfl_xor(s, off); sq += __shfl_xor(sq, off); }
    __shared__ float red[8];
    int w = t >> 6, lane = t & 63;
    if (lane == 0) { red[w] = s; red[4 + w] = sq; }
    __syncthreads();
    s  = red[0] + red[1] + red[2] + red[3];
    sq = red[4] + red[5] + red[6] + red[7];
    float m   = s * (1.f / D);
    float inv = rsqrtf(sq * (1.f / D) - m * m + 1e-5f);
    float v0 = (e0 - m) * inv * sc[t]       + bi[t];
    float v1 = (e1 - m) * inv * sc[t + 256] + bi[t + 256];
    float v2 = (e2 - m) * inv * sc[t + 512] + bi[t + 512];
    if (outB) {
        short* o = outB + (size_t)row * D;
        o[t] = f2b(v0); o[t + 256] = f2b(v1); o[t + 512] = f2b(v2);
    } else {
        float* o = outF + (size_t)row * D;
        o[t] = v0; o[t + 256] = v1; o[t + 512] = v2;
    }
}

// ---------------------------------------------------------------------------
// bf16 MFMA GEMM with global_load_lds staging (round-3 structure).
// ---------------------------------------------------------------------------
__global__ __launch_bounds__(256) void gemm_bf(
    const short* __restrict__ A, const short* __restrict__ Wt,
    const float* __restrict__ Bb0, const float* __restrict__ Bb1, const float* __restrict__ Bb2,
    float* __restrict__ outF, const float* __restrict__ resid,
    short* __restrict__ outB,
    int K, int nper, float alpha0, int mode)
{
    __shared__ __align__(16) short As[128 * 32];
    __shared__ __align__(16) short Bs[128 * 32];
    int tid  = threadIdx.x;
    int lane = tid & 63;
    int w    = tid >> 6;
    int row0 = blockIdx.x * 128;
    int n0   = blockIdx.y * 128;
    int which = n0 / nper;
    int ncol0 = n0 - which * nper;
    const float* Bv = (which == 0) ? Bb0 : ((which == 1) ? Bb1 : Bb2);
    float alpha = (which == 0) ? alpha0 : 1.0f;

    int wr = (w >> 1) * 64;
    int wc = (w & 1) * 64;
    int fr = lane & 15;
    int kb8 = (lane >> 4) * 8;

    int sr = tid >> 2, skk = (tid & 3) * 8;

    f32x4 acc[4][4] = {};

    for (int k0 = 0; k0 < K; k0 += 32) {
        #pragma unroll
        for (int i = 0; i < 2; ++i) {
            int r = i * 64 + sr;
            gload16(A  + (size_t)(row0 + r) * K + k0 + skk,
                    (char*)As + ((size_t)i * 256 + w * 64) * 16);
            gload16(Wt + (size_t)(n0 + r) * K + k0 + skk,
                    (char*)Bs + ((size_t)i * 256 + w * 64) * 16);
        }
        __syncthreads();
        bf16x8 af[4], bfr[4];
        #pragma unroll
        for (int m = 0; m < 4; ++m) af[m]  = *(const bf16x8*)&As[(wr + m * 16 + fr) * 32 + kb8];
        #pragma unroll
        for (int n = 0; n < 4; ++n) bfr[n] = *(const bf16x8*)&Bs[(wc + n * 16 + fr) * 32 + kb8];
        #pragma unroll
        for (int m = 0; m < 4; ++m)
            #pragma unroll
            for (int n = 0; n < 4; ++n)
                acc[m][n] = __builtin_amdgcn_mfma_f32_16x16x32_bf16(af[m], bfr[n], acc[m][n], 0, 0, 0);
        __syncthreads();
    }

    int rr = (lane >> 4) * 4;
    if (mode == 1) {
        short* base = outB + (size_t)which * ROWS * D;
        #pragma unroll
        for (int m = 0; m < 4; ++m) {
            int rowb = row0 + wr + m * 16 + rr;
            int b2 = rowb >> 9, s0 = rowb & 511;
            #pragma unroll
            for (int n = 0; n < 4; ++n) {
                int col = ncol0 + wc + n * 16 + fr;
                int h2 = col >> 6, d2 = col & 63;
                float bv = Bv[col];
                if (which == 2) {
                    bf16x4 pk;
                    #pragma unroll
                    for (int ri = 0; ri < 4; ++ri) pk[ri] = f2b(acc[m][n][ri] + bv);
                    *(bf16x4*)&base[(((size_t)b2 * H + h2) * 64 + d2) * 512 + s0] = pk;
                } else {
                    #pragma unroll
                    for (int ri = 0; ri < 4; ++ri)
                        base[(((size_t)b2 * H + h2) * 512 + (s0 + ri)) * 64 + d2] =
                            f2b((acc[m][n][ri] + bv) * alpha);
                }
            }
        }
        return;
    }

    #pragma unroll
    for (int m = 0; m < 4; ++m) {
        #pragma unroll
        for (int n = 0; n < 4; ++n) {
            int col  = ncol0 + wc + n * 16 + fr;
            float bv = Bv[col];
            #pragma unroll
            for (int ri = 0; ri < 4; ++ri) {
                int row = row0 + wr + m * 16 + rr + ri;
                size_t idx = (size_t)row * nper + col;
                float val = acc[m][n][ri] + bv;
                if (mode == 2) {
                    outB[idx] = f2b(gelu_f(val));
                } else {
                    outF[idx] = val + resid[idx];
                }
            }
        }
    }
}

// ---------------------------------------------------------------------------
// MFMA attention. XCD swizzle: b = bid&7 (batch==XCD), hh = bid>>6,
// qblk = (bid>>3)&7. Bias from packed u32 tensor.
// ---------------------------------------------------------------------------
__global__ __launch_bounds__(256) void attn_kernel(
    const short* __restrict__ qb, const short* __restrict__ kbuf,
    const short* __restrict__ vtb,
    const uint32_t* __restrict__ pb,
    const float* __restrict__ vd, const float* __restrict__ ac,
    short* __restrict__ o)
{
    __shared__ __align__(16) short pl[4][16][520];
    int tid = threadIdx.x, lane = tid & 63, w = tid >> 6;
    int bid = blockIdx.x;
    int b    = bid & 7;          // batch == XCD slot
    int qblk = (bid >> 3) & 7;
    int hh   = bid >> 6;
    int fr = lane & 15, g16 = lane >> 4;
    int kb8 = g16 * 8, rr = g16 * 4;
    int i0 = qblk * 64 + w * 16;

    const short* qp = qb   + ((size_t)(b * H + hh) * S) * 64;
    const short* kp = kbuf + ((size_t)(b * H + hh) * S) * 64;
    const short* vp = vtb  + ((size_t)(b * H + hh) * 64) * S;

    bf16x8 aq0 = *(const bf16x8*)&qp[(i0 + fr) * 64 + kb8];
    bf16x8 aq1 = *(const bf16x8*)&qp[(i0 + fr) * 64 + 32 + kb8];

    f32x4 s[32];
    #pragma unroll
    for (int jt = 0; jt < 32; ++jt) {
        bf16x8 kf0 = *(const bf16x8*)&kp[(jt * 16 + fr) * 64 + kb8];
        bf16x8 kf1 = *(const bf16x8*)&kp[(jt * 16 + fr) * 64 + 32 + kb8];
        f32x4 a = {};
        a = __builtin_amdgcn_mfma_f32_16x16x32_bf16(aq0, kf0, a, 0, 0, 0);
        s[jt] = __builtin_amdgcn_mfma_f32_16x16x32_bf16(aq1, kf1, a, 0, 0, 0);
    }

    float Ah = ac[hh], Ch = ac[16 + hh], th = vd[hh];
    const uint32_t* pbb = pb + (size_t)b * S * S;
    #pragma unroll
    for (int jt = 0; jt < 32; ++jt) {
        int j = jt * 16 + fr;
        #pragma unroll
        for (int ri = 0; ri < 4; ++ri) {
            int i = i0 + rr + ri;
            uint32_t u = pbb[(size_t)i * S + j];
            float bias = b2f_lo(u);
            if (i > 0 && j > 0) bias += b2f_hi(u) * Ah + Ch;
            if (i == 0 || j == 0) bias += th;
            s[jt][ri] += bias;
        }
    }

    float invl[4];
    #pragma unroll
    for (int ri = 0; ri < 4; ++ri) {
        float mx = s[0][ri];
        #pragma unroll
        for (int jt = 1; jt < 32; ++jt) mx = fmaxf(mx, s[jt][ri]);
        mx = fmaxf(mx, __shfl_xor(mx, 1));
        mx = fmaxf(mx, __shfl_xor(mx, 2));
        mx = fmaxf(mx, __shfl_xor(mx, 4));
        mx = fmaxf(mx, __shfl_xor(mx, 8));
        float l = 0.f;
        #pragma unroll
        for (int jt = 0; jt < 32; ++jt) { float p = __expf(s[jt][ri] - mx); s[jt][ri] = p; l += p; }
        l += __shfl_xor(l, 1); l += __shfl_xor(l, 2);
        l += __shfl_xor(l, 4); l += __shfl_xor(l, 8);
        invl[ri] = 1.f / l;
    }

    #pragma unroll
    for (int jt = 0; jt < 32; ++jt)
        #pragma unroll
        for (int ri = 0; ri < 4; ++ri)
            pl[w][rr + ri][jt * 16 + fr] = f2b(s[jt][ri]);

    f32x4 oacc[4] = {};
    #pragma unroll
    for (int jt2 = 0; jt2 < 16; ++jt2) {
        bf16x8 pa = *(const bf16x8*)&pl[w][fr][jt2 * 32 + kb8];
        #pragma unroll
        for (int dt = 0; dt < 4; ++dt) {
            bf16x8 pb2 = *(const bf16x8*)&vp[(dt * 16 + fr) * S + jt2 * 32 + kb8];
            oacc[dt] = __builtin_amdgcn_mfma_f32_16x16x32_bf16(pa, pb2, oacc[dt], 0, 0, 0);
        }
    }
    #pragma unroll
    for (int dt = 0; dt < 4; ++dt)
        #pragma unroll
        for (int ri = 0; ri < 4; ++ri)
            o[((size_t)(b * S + i0 + rr + ri) * H + hh) * 64 + dt * 16 + fr] = f2b(oacc[dt][ri] * invl[ri]);
}

// ---------------------------------------------------------------------------
extern "C" void kernel_launch(void* const* d_in, const int* in_sizes, int n_in,
                              void* d_out, int out_size, void* d_ws, size_t ws_size,
                              hipStream_t stream)
{
    const float* attn_bias   = (const float*)d_in[0];
    const float* spatial_pos = (const float*)d_in[1];
    const int*   xx          = (const int*)d_in[2];
    const float* node_emb    = (const float*)d_in[3];
    const float* graph_token = (const float*)d_in[4];
    const float* virt_dist   = (const float*)d_in[5];
    const float* sp_w1 = (const float*)d_in[6];
    const float* sp_b1 = (const float*)d_in[7];
    const float* sp_w2 = (const float*)d_in[8];
    const float* sp_b2 = (const float*)d_in[9];
    const float* ln1_s = (const float*)d_in[10];
    const float* ln1_b = (const float*)d_in[11];
    const float* wq = (const float*)d_in[12];
    const float* bq = (const float*)d_in[13];
    const float* wk = (const float*)d_in[14];
    const float* bk = (const float*)d_in[15];
    const float* wv = (const float*)d_in[16];
    const float* bv = (const float*)d_in[17];
    const float* wo = (const float*)d_in[18];
    const float* bo = (const float*)d_in[19];
    const float* ln2_s = (const float*)d_in[20];
    const float* ln2_b = (const float*)d_in[21];
    const float* fw1 = (const float*)d_in[22];
    const float* fb1 = (const float*)d_in[23];
    const float* fw2 = (const float*)d_in[24];
    const float* fb2 = (const float*)d_in[25];
    const float* fln_s = (const float*)d_in[26];
    const float* fln_b = (const float*)d_in[27];

    float* wsf = (float*)d_ws;
    const size_t SZ = (size_t)ROWS * D;        // 3,145,728
    float* h   = wsf;                          // f32 [ROWS][D]
    float* acb = wsf + SZ;                     // A[12],C[12]
    short* s16 = (short*)(wsf + SZ + 64);
    short* yob = s16;                          // bf16 [ROWS][D]
    short* g16 = s16 + SZ;                     // bf16 [ROWS][FFN]
    short* bfq = g16 + (size_t)ROWS * FFN;     // 3 x bf16 [ROWS*D]
    short* wqkvT = bfq + 3 * SZ;               // [2304][768]
    short* woT   = wqkvT + 2304 * 768;         // [768][768]
    short* f1T   = woT + 768 * 768;            // [3072][768]
    short* f2T   = f1T + (size_t)3072 * 768;   // [768][3072]
    uint32_t* pbias = (uint32_t*)(f2T + (size_t)768 * 3072);  // [B][S][S] u32

    embed_kernel<<<ROWS, 256, 0, stream>>>(xx, node_emb, graph_token, h);
    ac_kernel<<<1, 64, 0, stream>>>(sp_w1, sp_b1, sp_w2, sp_b2, acb);
    bias_pack_kernel<<<ROWS, 256, 0, stream>>>(attn_bias, spatial_pos, pbias);

    for (int l = 0; l < 6; ++l) {
        wcvt_kernel<<<1728, 256, 0, stream>>>(
            wq + (size_t)l * D * D, wk + (size_t)l * D * D, wv + (size_t)l * D * D,
            wo + (size_t)l * D * D, fw1 + (size_t)l * D * FFN, fw2 + (size_t)l * FFN * D,
            wqkvT, woT, f1T, f2T);
        ln_kernel<<<ROWS, 256, 0, stream>>>(h, ln1_s + l * D, ln1_b + l * D, nullptr, yob);
        gemm_bf<<<dim3(32, 18), 256, 0, stream>>>(
            yob, wqkvT, bq + l * D, bk + l * D, bv + l * D,
            nullptr, nullptr, bfq, D, D, 0.125f, 1);
        attn_kernel<<<B * H * 8, 256, 0, stream>>>(
            bfq, bfq + SZ, bfq + 2 * SZ, pbias, virt_dist, acb, yob);
        gemm_bf<<<dim3(32, 6), 256, 0, stream>>>(
            yob, woT, bo + l * D, nullptr, nullptr,
            h, h, nullptr, D, D, 1.0f, 0);
        ln_kernel<<<ROWS, 256, 0, stream>>>(h, ln2_s + l * D, ln2_b + l * D, nullptr, yob);
        gemm_bf<<<dim3(32, 24), 256, 0, stream>>>(
            yob, f1T, fb1 + l * FFN, nullptr, nullptr,
            nullptr, nullptr, g16, D, FFN, 1.0f, 2);
        gemm_bf<<<dim3(32, 6), 256, 0, stream>>>(
            g16, f2T, fb2 + l * D, nullptr, nullptr,
            h, h, nullptr, FFN, D, 1.0f, 0);
    }
    ln_kernel<<<ROWS, 256, 0, stream>>>(h, fln_s, fln_b, (float*)d_out, nullptr);
}

// Round 6
// 1476.202 us; speedup vs baseline: 4.6830x; 1.1261x over previous
//
#include <hip/hip_runtime.h>
#include <cstdint>
#include <cstddef>

// ---------------------------------------------------------------------------
// Graphormer-ish encoder forward, MI355X (gfx950).
// Round 5: GEMM 2-phase pipeline (double-buffered LDS, stage-next-before-
// compute, ONE barrier per K-step via __syncthreads' vmcnt drain), BM=64
// tiles for the 192-block GEMMs (device fill), bijective XCD chunking of
// the GEMM grid (weight-panel L2 locality).
// ---------------------------------------------------------------------------

typedef __attribute__((ext_vector_type(8))) short bf16x8;
typedef __attribute__((ext_vector_type(4))) short bf16x4;
typedef __attribute__((ext_vector_type(4))) float f32x4;

static constexpr int D    = 768;
static constexpr int H    = 12;
static constexpr int S    = 512;
static constexpr int NN   = 511;
static constexpr int B    = 8;
static constexpr int FFN  = 3072;
static constexpr int ROWS = B * S;   // 4096

__device__ __forceinline__ short f2b(float x) {
    union { float f; uint32_t u; } c; c.f = x;
    uint32_t r = (c.u + 0x7fffu + ((c.u >> 16) & 1u)) >> 16;  // RNE
    return (short)(uint16_t)r;
}
__device__ __forceinline__ float b2f_lo(uint32_t u) {
    union { uint32_t u; float f; } c; c.u = u << 16; return c.f;
}
__device__ __forceinline__ float b2f_hi(uint32_t u) {
    union { uint32_t u; float f; } c; c.u = u & 0xffff0000u; return c.f;
}
__device__ __forceinline__ float gelu_f(float x) {
    return 0.5f * x * (1.0f + erff(x * 0.7071067811865476f));
}
__device__ __forceinline__ void gload16(const void* g, void* l) {
    __builtin_amdgcn_global_load_lds(
        (const __attribute__((address_space(1))) void*)g,
        (__attribute__((address_space(3))) void*)l, 16, 0, 0);
}

// ---------------------------------------------------------------------------
__global__ __launch_bounds__(256) void embed_kernel(
    const int* __restrict__ x, const float* __restrict__ emb,
    const float* __restrict__ gtok, float* __restrict__ h)
{
    int row = blockIdx.x;
    int b = row >> 9, s = row & (S - 1);
    const float* src = (s == 0) ? gtok : (emb + (size_t)x[b * NN + (s - 1)] * D);
    float* dst = h + (size_t)row * D;
    int t = threadIdx.x;
    dst[t]       = src[t];
    dst[t + 256] = src[t + 256];
    dst[t + 512] = src[t + 512];
}

// ---------------------------------------------------------------------------
__global__ void ac_kernel(const float* __restrict__ w1, const float* __restrict__ b1,
                          const float* __restrict__ w2, const float* __restrict__ b2,
                          float* __restrict__ ac)
{
    int h = threadIdx.x;
    if (h < H) {
        float a = 0.f, c = 0.f;
        for (int k = 0; k < 128; ++k) { a += w1[k] * w2[k * H + h]; c += b1[k] * w2[k * H + h]; }
        ac[h] = a; ac[16 + h] = c + b2[h];
    }
}

// ---------------------------------------------------------------------------
// pb[b,i,j] = u32( bf16(2*ab) | bf16(sp_interior)<<16 )
// ---------------------------------------------------------------------------
__global__ __launch_bounds__(256) void bias_pack_kernel(
    const float* __restrict__ ab, const float* __restrict__ sp,
    uint32_t* __restrict__ pb)
{
    int row = blockIdx.x;                 // b*S + i
    int b = row >> 9, i = row & 511;
    const float* abr = ab + (size_t)row * S;
    const float* spr = sp + ((size_t)b * NN + (i - 1)) * NN;
    uint32_t* out = pb + (size_t)row * S;
    #pragma unroll
    for (int jt = 0; jt < 2; ++jt) {
        int j = jt * 256 + threadIdx.x;
        float a2 = 2.f * abr[j];
        float spv = (i > 0 && j > 0) ? spr[j - 1] : 0.f;
        out[j] = (uint32_t)(uint16_t)f2b(a2) | ((uint32_t)(uint16_t)f2b(spv) << 16);
    }
}

// ---------------------------------------------------------------------------
// Per-layer weight convert+transpose: f32 [R][C] -> bf16 [C][R].
// ---------------------------------------------------------------------------
__global__ __launch_bounds__(256) void wcvt_kernel(
    const float* __restrict__ wq, const float* __restrict__ wk,
    const float* __restrict__ wv, const float* __restrict__ wo,
    const float* __restrict__ f1, const float* __restrict__ f2,
    short* __restrict__ wqkvT, short* __restrict__ woT,
    short* __restrict__ f1T, short* __restrict__ f2T)
{
    int t = blockIdx.x;
    const float* in; short* out; int R, C, tr, tc;
    if (t < 432) {
        int which = t / 144, tt = t - which * 144;
        in = (which == 0) ? wq : ((which == 1) ? wk : wv);
        out = wqkvT + (size_t)which * 768 * 768;
        R = 768; C = 768; tr = tt / 12; tc = tt % 12;
    } else if (t < 576) {
        int tt = t - 432; in = wo; out = woT; R = 768; C = 768; tr = tt / 12; tc = tt % 12;
    } else if (t < 1152) {
        int tt = t - 576; in = f1; out = f1T; R = 768; C = 3072; tr = tt / 48; tc = tt % 48;
    } else {
        int tt = t - 1152; in = f2; out = f2T; R = 3072; C = 768; tr = tt / 12; tc = tt % 12;
    }
    int r0 = tr * 64, c0 = tc * 64;
    __shared__ short tile[64][65];
    int tid = threadIdx.x;
    #pragma unroll
    for (int i = 0; i < 16; ++i) {
        int e = i * 256 + tid; int r = e >> 6, c = e & 63;
        tile[r][c] = f2b(in[(size_t)(r0 + r) * C + c0 + c]);
    }
    __syncthreads();
    #pragma unroll
    for (int i = 0; i < 16; ++i) {
        int e = i * 256 + tid; int c = e >> 6, r = e & 63;
        out[(size_t)(c0 + c) * R + r0 + r] = tile[r][c];
    }
}

// ---------------------------------------------------------------------------
__global__ __launch_bounds__(256) void ln_kernel(
    const float* __restrict__ in, const float* __restrict__ sc,
    const float* __restrict__ bi, float* __restrict__ outF,
    short* __restrict__ outB)
{
    int row = blockIdx.x, t = threadIdx.x;
    const float* x = in + (size_t)row * D;
    float e0 = x[t], e1 = x[t + 256], e2 = x[t + 512];
    float s  = e0 + e1 + e2;
    float sq = e0 * e0 + e1 * e1 + e2 * e2;
    #pragma unroll
    for (int off = 1; off < 64; off <<= 1) { s += __shfl_xor(s, off); sq += __shfl_xor(sq, off); }
    __shared__ float red[8];
    int w = t >> 6, lane = t & 63;
    if (lane == 0) { red[w] = s; red[4 + w] = sq; }
    __syncthreads();
    s  = red[0] + red[1] + red[2] + red[3];
    sq = red[4] + red[5] + red[6] + red[7];
    float m   = s * (1.f / D);
    float inv = rsqrtf(sq * (1.f / D) - m * m + 1e-5f);
    float v0 = (e0 - m) * inv * sc[t]       + bi[t];
    float v1 = (e1 - m) * inv * sc[t + 256] + bi[t + 256];
    float v2 = (e2 - m) * inv * sc[t + 512] + bi[t + 512];
    if (outB) {
        short* o = outB + (size_t)row * D;
        o[t] = f2b(v0); o[t + 256] = f2b(v1); o[t + 512] = f2b(v2);
    } else {
        float* o = outF + (size_t)row * D;
        o[t] = v0; o[t + 256] = v1; o[t + 512] = v2;
    }
}

// ---------------------------------------------------------------------------
// 2-phase bf16 MFMA GEMM. BM x 128 tile, 4 waves (2x2), double-buffered LDS,
// stage(next) issued BEFORE compute(cur); one __syncthreads per K-step
// (its vmcnt(0)+lgkmcnt(0) drain is the pipeline fence).
// Grid: 1D, col-major tiles, bijective XCD chunking (nwg % 8 == 0).
// mode 0: f32 out + resid.  mode 1: QKV bf16 layouts.  mode 2: bf16 gelu out.
// ---------------------------------------------------------------------------
template<int BM>
__global__ __launch_bounds__(256) void gemm2(
    const short* __restrict__ A, const short* __restrict__ Wt,
    const float* __restrict__ Bb0, const float* __restrict__ Bb1, const float* __restrict__ Bb2,
    float* __restrict__ outF, const float* __restrict__ resid,
    short* __restrict__ outB,
    int K, int nper, int gx, float alpha0, int mode)
{
    constexpr int MR = BM / 32;             // m-frags per wave (wave covers BM/2 rows)
    __shared__ __align__(16) short As[2][BM * 32];
    __shared__ __align__(16) short Bs[2][128 * 32];
    int tid  = threadIdx.x;
    int lane = tid & 63;
    int w    = tid >> 6;

    int nwg = gridDim.x;
    int bid = blockIdx.x;
    int sid = (bid & 7) * (nwg >> 3) + (bid >> 3);   // XCD-chunked, bijective
    int row0 = (sid % gx) * BM;
    int n0   = (sid / gx) * 128;

    int which = n0 / nper;
    int ncol0 = n0 - which * nper;
    const float* Bv = (which == 0) ? Bb0 : ((which == 1) ? Bb1 : Bb2);
    float alpha = (which == 0) ? alpha0 : 1.0f;

    int wr = (w >> 1) * (BM / 2);
    int wc = (w & 1) * 64;
    int fr = lane & 15;
    int kb8 = (lane >> 4) * 8;
    int sr = tid >> 2, skk = (tid & 3) * 8;

    f32x4 acc[MR][4] = {};

    auto stage = [&](int buf, int k0) {
        #pragma unroll
        for (int i = 0; i < BM / 64; ++i)
            gload16(A + (size_t)(row0 + i * 64 + sr) * K + k0 + skk,
                    (char*)&As[buf][0] + ((size_t)i * 256 + w * 64) * 16);
        #pragma unroll
        for (int i = 0; i < 2; ++i)
            gload16(Wt + (size_t)(n0 + i * 64 + sr) * K + k0 + skk,
                    (char*)&Bs[buf][0] + ((size_t)i * 256 + w * 64) * 16);
    };
    auto compute = [&](int buf) {
        bf16x8 af[MR], bfr[4];
        #pragma unroll
        for (int m = 0; m < MR; ++m) af[m]  = *(const bf16x8*)&As[buf][(wr + m * 16 + fr) * 32 + kb8];
        #pragma unroll
        for (int n = 0; n < 4; ++n) bfr[n] = *(const bf16x8*)&Bs[buf][(wc + n * 16 + fr) * 32 + kb8];
        #pragma unroll
        for (int m = 0; m < MR; ++m)
            #pragma unroll
            for (int n = 0; n < 4; ++n)
                acc[m][n] = __builtin_amdgcn_mfma_f32_16x16x32_bf16(af[m], bfr[n], acc[m][n], 0, 0, 0);
    };

    int nt = K >> 5;
    stage(0, 0);
    __syncthreads();                         // drain: buf0 staged
    int cur = 0;
    for (int t = 1; t < nt; ++t) {
        stage(cur ^ 1, t * 32);              // in flight during compute(cur)
        compute(cur);
        __syncthreads();                     // drain: next staged; cur reads consumed
        cur ^= 1;
    }
    compute(cur);

    int rr = (lane >> 4) * 4;
    if (mode == 1) {
        short* base = outB + (size_t)which * ROWS * D;
        #pragma unroll
        for (int m = 0; m < MR; ++m) {
            int rowb = row0 + wr + m * 16 + rr;
            int b2 = rowb >> 9, s0 = rowb & 511;
            #pragma unroll
            for (int n = 0; n < 4; ++n) {
                int col = ncol0 + wc + n * 16 + fr;
                int h2 = col >> 6, d2 = col & 63;
                float bv = Bv[col];
                if (which == 2) {
                    bf16x4 pk;
                    #pragma unroll
                    for (int ri = 0; ri < 4; ++ri) pk[ri] = f2b(acc[m][n][ri] + bv);
                    *(bf16x4*)&base[(((size_t)b2 * H + h2) * 64 + d2) * 512 + s0] = pk;
                } else {
                    #pragma unroll
                    for (int ri = 0; ri < 4; ++ri)
                        base[(((size_t)b2 * H + h2) * 512 + (s0 + ri)) * 64 + d2] =
                            f2b((acc[m][n][ri] + bv) * alpha);
                }
            }
        }
        return;
    }

    #pragma unroll
    for (int m = 0; m < MR; ++m) {
        #pragma unroll
        for (int n = 0; n < 4; ++n) {
            int col  = ncol0 + wc + n * 16 + fr;
            float bv = Bv[col];
            #pragma unroll
            for (int ri = 0; ri < 4; ++ri) {
                int row = row0 + wr + m * 16 + rr + ri;
                size_t idx = (size_t)row * nper + col;
                float val = acc[m][n][ri] + bv;
                if (mode == 2) {
                    outB[idx] = f2b(gelu_f(val));
                } else {
                    outF[idx] = val + resid[idx];
                }
            }
        }
    }
}

// ---------------------------------------------------------------------------
// MFMA attention (round-4 structure): XCD swizzle (batch==XCD), packed bias.
// ---------------------------------------------------------------------------
__global__ __launch_bounds__(256) void attn_kernel(
    const short* __restrict__ qb, const short* __restrict__ kbuf,
    const short* __restrict__ vtb,
    const uint32_t* __restrict__ pb,
    const float* __restrict__ vd, const float* __restrict__ ac,
    short* __restrict__ o)
{
    __shared__ __align__(16) short pl[4][16][520];
    int tid = threadIdx.x, lane = tid & 63, w = tid >> 6;
    int bid = blockIdx.x;
    int b    = bid & 7;
    int qblk = (bid >> 3) & 7;
    int hh   = bid >> 6;
    int fr = lane & 15, g16 = lane >> 4;
    int kb8 = g16 * 8, rr = g16 * 4;
    int i0 = qblk * 64 + w * 16;

    const short* qp = qb   + ((size_t)(b * H + hh) * S) * 64;
    const short* kp = kbuf + ((size_t)(b * H + hh) * S) * 64;
    const short* vp = vtb  + ((size_t)(b * H + hh) * 64) * S;

    bf16x8 aq0 = *(const bf16x8*)&qp[(i0 + fr) * 64 + kb8];
    bf16x8 aq1 = *(const bf16x8*)&qp[(i0 + fr) * 64 + 32 + kb8];

    f32x4 s[32];
    #pragma unroll
    for (int jt = 0; jt < 32; ++jt) {
        bf16x8 kf0 = *(const bf16x8*)&kp[(jt * 16 + fr) * 64 + kb8];
        bf16x8 kf1 = *(const bf16x8*)&kp[(jt * 16 + fr) * 64 + 32 + kb8];
        f32x4 a = {};
        a = __builtin_amdgcn_mfma_f32_16x16x32_bf16(aq0, kf0, a, 0, 0, 0);
        s[jt] = __builtin_amdgcn_mfma_f32_16x16x32_bf16(aq1, kf1, a, 0, 0, 0);
    }

    float Ah = ac[hh], Ch = ac[16 + hh], th = vd[hh];
    const uint32_t* pbb = pb + (size_t)b * S * S;
    #pragma unroll
    for (int jt = 0; jt < 32; ++jt) {
        int j = jt * 16 + fr;
        #pragma unroll
        for (int ri = 0; ri < 4; ++ri) {
            int i = i0 + rr + ri;
            uint32_t u = pbb[(size_t)i * S + j];
            float bias = b2f_lo(u);
            if (i > 0 && j > 0) bias += b2f_hi(u) * Ah + Ch;
            if (i == 0 || j == 0) bias += th;
            s[jt][ri] += bias;
        }
    }

    float invl[4];
    #pragma unroll
    for (int ri = 0; ri < 4; ++ri) {
        float mx = s[0][ri];
        #pragma unroll
        for (int jt = 1; jt < 32; ++jt) mx = fmaxf(mx, s[jt][ri]);
        mx = fmaxf(mx, __shfl_xor(mx, 1));
        mx = fmaxf(mx, __shfl_xor(mx, 2));
        mx = fmaxf(mx, __shfl_xor(mx, 4));
        mx = fmaxf(mx, __shfl_xor(mx, 8));
        float l = 0.f;
        #pragma unroll
        for (int jt = 0; jt < 32; ++jt) { float p = __expf(s[jt][ri] - mx); s[jt][ri] = p; l += p; }
        l += __shfl_xor(l, 1); l += __shfl_xor(l, 2);
        l += __shfl_xor(l, 4); l += __shfl_xor(l, 8);
        invl[ri] = 1.f / l;
    }

    #pragma unroll
    for (int jt = 0; jt < 32; ++jt)
        #pragma unroll
        for (int ri = 0; ri < 4; ++ri)
            pl[w][rr + ri][jt * 16 + fr] = f2b(s[jt][ri]);

    f32x4 oacc[4] = {};
    #pragma unroll
    for (int jt2 = 0; jt2 < 16; ++jt2) {
        bf16x8 pa = *(const bf16x8*)&pl[w][fr][jt2 * 32 + kb8];
        #pragma unroll
        for (int dt = 0; dt < 4; ++dt) {
            bf16x8 pb2 = *(const bf16x8*)&vp[(dt * 16 + fr) * S + jt2 * 32 + kb8];
            oacc[dt] = __builtin_amdgcn_mfma_f32_16x16x32_bf16(pa, pb2, oacc[dt], 0, 0, 0);
        }
    }
    #pragma unroll
    for (int dt = 0; dt < 4; ++dt)
        #pragma unroll
        for (int ri = 0; ri < 4; ++ri)
            o[((size_t)(b * S + i0 + rr + ri) * H + hh) * 64 + dt * 16 + fr] = f2b(oacc[dt][ri] * invl[ri]);
}

// ---------------------------------------------------------------------------
extern "C" void kernel_launch(void* const* d_in, const int* in_sizes, int n_in,
                              void* d_out, int out_size, void* d_ws, size_t ws_size,
                              hipStream_t stream)
{
    const float* attn_bias   = (const float*)d_in[0];
    const float* spatial_pos = (const float*)d_in[1];
    const int*   xx          = (const int*)d_in[2];
    const float* node_emb    = (const float*)d_in[3];
    const float* graph_token = (const float*)d_in[4];
    const float* virt_dist   = (const float*)d_in[5];
    const float* sp_w1 = (const float*)d_in[6];
    const float* sp_b1 = (const float*)d_in[7];
    const float* sp_w2 = (const float*)d_in[8];
    const float* sp_b2 = (const float*)d_in[9];
    const float* ln1_s = (const float*)d_in[10];
    const float* ln1_b = (const float*)d_in[11];
    const float* wq = (const float*)d_in[12];
    const float* bq = (const float*)d_in[13];
    const float* wk = (const float*)d_in[14];
    const float* bk = (const float*)d_in[15];
    const float* wv = (const float*)d_in[16];
    const float* bv = (const float*)d_in[17];
    const float* wo = (const float*)d_in[18];
    const float* bo = (const float*)d_in[19];
    const float* ln2_s = (const float*)d_in[20];
    const float* ln2_b = (const float*)d_in[21];
    const float* fw1 = (const float*)d_in[22];
    const float* fb1 = (const float*)d_in[23];
    const float* fw2 = (const float*)d_in[24];
    const float* fb2 = (const float*)d_in[25];
    const float* fln_s = (const float*)d_in[26];
    const float* fln_b = (const float*)d_in[27];

    float* wsf = (float*)d_ws;
    const size_t SZ = (size_t)ROWS * D;        // 3,145,728
    float* h   = wsf;                          // f32 [ROWS][D]
    float* acb = wsf + SZ;                     // A[12],C[12]
    short* s16 = (short*)(wsf + SZ + 64);
    short* yob = s16;                          // bf16 [ROWS][D]
    short* g16 = s16 + SZ;                     // bf16 [ROWS][FFN]
    short* bfq = g16 + (size_t)ROWS * FFN;     // 3 x bf16 [ROWS*D]
    short* wqkvT = bfq + 3 * SZ;               // [2304][768]
    short* woT   = wqkvT + 2304 * 768;         // [768][768]
    short* f1T   = woT + 768 * 768;            // [3072][768]
    short* f2T   = f1T + (size_t)3072 * 768;   // [768][3072]
    uint32_t* pbias = (uint32_t*)(f2T + (size_t)768 * 3072);  // [B][S][S] u32

    embed_kernel<<<ROWS, 256, 0, stream>>>(xx, node_emb, graph_token, h);
    ac_kernel<<<1, 64, 0, stream>>>(sp_w1, sp_b1, sp_w2, sp_b2, acb);
    bias_pack_kernel<<<ROWS, 256, 0, stream>>>(attn_bias, spatial_pos, pbias);

    for (int l = 0; l < 6; ++l) {
        wcvt_kernel<<<1728, 256, 0, stream>>>(
            wq + (size_t)l * D * D, wk + (size_t)l * D * D, wv + (size_t)l * D * D,
            wo + (size_t)l * D * D, fw1 + (size_t)l * D * FFN, fw2 + (size_t)l * FFN * D,
            wqkvT, woT, f1T, f2T);
        ln_kernel<<<ROWS, 256, 0, stream>>>(h, ln1_s + l * D, ln1_b + l * D, nullptr, yob);
        // QKV: 32 row-tiles x 18 col-tiles = 576 blocks
        gemm2<128><<<576, 256, 0, stream>>>(
            yob, wqkvT, bq + l * D, bk + l * D, bv + l * D,
            nullptr, nullptr, bfq, D, D, 32, 0.125f, 1);
        attn_kernel<<<B * H * 8, 256, 0, stream>>>(
            bfq, bfq + SZ, bfq + 2 * SZ, pbias, virt_dist, acb, yob);
        // o-proj: 64 x 6 = 384 blocks (BM=64)
        gemm2<64><<<384, 256, 0, stream>>>(
            yob, woT, bo + l * D, nullptr, nullptr,
            h, h, nullptr, D, D, 64, 1.0f, 0);
        ln_kernel<<<ROWS, 256, 0, stream>>>(h, ln2_s + l * D, ln2_b + l * D, nullptr, yob);
        // FFN1: 32 x 24 = 768 blocks
        gemm2<128><<<768, 256, 0, stream>>>(
            yob, f1T, fb1 + l * FFN, nullptr, nullptr,
            nullptr, nullptr, g16, D, FFN, 32, 1.0f, 2);
        // FFN2: 64 x 6 = 384 blocks (BM=64)
        gemm2<64><<<384, 256, 0, stream>>>(
            g16, f2T, fb2 + l * D, nullptr, nullptr,
            h, h, nullptr, FFN, D, 64, 1.0f, 0);
    }
    ln_kernel<<<ROWS, 256, 0, stream>>>(h, fln_s, fln_b, (float*)d_out, nullptr);
}